// Round 1
// baseline (433.563 us; speedup 1.0000x reference)
//
#include <hip/hip_runtime.h>
#include <math.h>

// GraphConvLayer fused kernel, round 1 (correctness + solid vectorization, all f32)
//
// Per block: BM=32 rows.
//  Stage 1: gather-mean neighbor feats (float4-coalesced), coord stats -> LDS mix[32][520]
//  Stage 2: register-tiled matvec: thread = 8 rows x 4 channels, W float4 loads (coalesced),
//           mix read as broadcast ds_read_b128. SiLU epilogue, float4 stores.

constexpr int K = 32;
constexpr int C = 256;
constexpr int IN_DIM = 2 * C + 6;    // 518
constexpr int BM = 32;               // rows per block
constexpr int MIX_STRIDE = 520;      // 16B-aligned row stride (520*4 % 16 == 0)
constexpr int NTHREADS = 256;

#define FMA4(mcomp, wv)                                                        \
  a.x = fmaf((mcomp), (wv).x, a.x);                                            \
  a.y = fmaf((mcomp), (wv).y, a.y);                                            \
  a.z = fmaf((mcomp), (wv).z, a.z);                                            \
  a.w = fmaf((mcomp), (wv).w, a.w);

__global__ __launch_bounds__(NTHREADS, 2)
void gcl_fused(const float* __restrict__ feat,
               const float* __restrict__ coords,
               const int*   __restrict__ knn,
               const float* __restrict__ W,
               const float* __restrict__ bias,
               float* __restrict__ out,
               int n)
{
  __shared__ float mix[BM][MIX_STRIDE];
  __shared__ int   knnLds[BM * K];

  const int t = threadIdx.x;
  const int row0 = blockIdx.x * BM;

  // ---- load this block's knn indices into LDS (coalesced) ----
  #pragma unroll
  for (int i = 0; i < (BM * K) / NTHREADS; ++i) {
    const int e = t + i * NTHREADS;       // 0..1023
    const int r = e >> 5;                 // e / K
    const int k = e & (K - 1);
    int grow = row0 + r; if (grow >= n) grow = n - 1;
    knnLds[e] = knn[(size_t)grow * K + k];
  }
  __syncthreads();

  const int c4 = t & 63;    // float4 slot within the row (64 x float4 = 256 floats)
  const int rg = t >> 6;    // row group 0..3 (one per wave)

  // ---- stage 1: gather-mean of neighbor features + self feature copy ----
  for (int ri = 0; ri < BM / 4; ++ri) {
    const int r = rg * (BM / 4) + ri;
    int grow = row0 + r; if (grow >= n) grow = n - 1;
    const int* ids = &knnLds[r * K];
    float sx = 0.f, sy = 0.f, sz = 0.f, sw = 0.f;
    #pragma unroll 8
    for (int k = 0; k < K; ++k) {
      const float4 f = *reinterpret_cast<const float4*>(feat + (size_t)ids[k] * C + c4 * 4);
      sx += f.x; sy += f.y; sz += f.z; sw += f.w;
    }
    const float4 self = *reinterpret_cast<const float4*>(feat + (size_t)grow * C + c4 * 4);
    float* mr = mix[r];
    *reinterpret_cast<float4*>(mr + c4 * 4) = self;
    const float inv = 1.0f / (float)K;
    float4 a; a.x = sx * inv; a.y = sy * inv; a.z = sz * inv; a.w = sw * inv;
    *reinterpret_cast<float4*>(mr + C + c4 * 4) = a;
  }

  // ---- stage 1b: relative coordinate statistics (96 threads, 1 per (row,dim)) ----
  if (t < BM * 3) {
    const int r = t / 3;
    const int d = t - r * 3;
    int grow = row0 + r; if (grow >= n) grow = n - 1;
    const int* ids = &knnLds[r * K];
    float s = 0.f, ss = 0.f;
    #pragma unroll 8
    for (int k = 0; k < K; ++k) {
      const float v = coords[(size_t)ids[k] * 3 + d];
      s += v; ss += v * v;
    }
    const float inv = 1.0f / (float)K;
    const float m = s * inv;
    // var(rel) == var(nbr): the center shift cancels
    const float var = ss * inv - m * m;
    mix[r][2 * C + d]     = m - coords[(size_t)grow * 3 + d];
    mix[r][2 * C + 3 + d] = sqrtf(fmaxf(var, 0.f));
  }
  __syncthreads();

  // ---- stage 2: matvec mix(518) @ W(518,256), thread = 8 rows x 4 channels ----
  const int c0 = (t & 63) * 4;
  const int rbase = rg * (BM / 4);

  float4 acc[BM / 4];
  {
    const float4 bv = *reinterpret_cast<const float4*>(bias + c0);
    #pragma unroll
    for (int ri = 0; ri < BM / 4; ++ri) acc[ri] = bv;
  }

  // main loop covers j in [0, 516)
  for (int jb = 0; jb < 129; ++jb) {
    const int j = jb * 4;
    const float4 w0 = *reinterpret_cast<const float4*>(W + (size_t)(j + 0) * C + c0);
    const float4 w1 = *reinterpret_cast<const float4*>(W + (size_t)(j + 1) * C + c0);
    const float4 w2 = *reinterpret_cast<const float4*>(W + (size_t)(j + 2) * C + c0);
    const float4 w3 = *reinterpret_cast<const float4*>(W + (size_t)(j + 3) * C + c0);
    #pragma unroll
    for (int ri = 0; ri < BM / 4; ++ri) {
      const float4 m4 = *reinterpret_cast<const float4*>(&mix[rbase + ri][j]);
      float4 a = acc[ri];
      FMA4(m4.x, w0)
      FMA4(m4.y, w1)
      FMA4(m4.z, w2)
      FMA4(m4.w, w3)
      acc[ri] = a;
    }
  }
  // tail j = 516, 517
  #pragma unroll
  for (int jt = IN_DIM - 2; jt < IN_DIM; ++jt) {
    const float4 w = *reinterpret_cast<const float4*>(W + (size_t)jt * C + c0);
    #pragma unroll
    for (int ri = 0; ri < BM / 4; ++ri) {
      const float m = mix[rbase + ri][jt];
      float4 a = acc[ri];
      FMA4(m, w)
      acc[ri] = a;
    }
  }

  // ---- epilogue: SiLU + store ----
  #pragma unroll
  for (int ri = 0; ri < BM / 4; ++ri) {
    const int grow = row0 + rbase + ri;
    if (grow < n) {
      float4 a = acc[ri];
      a.x = a.x / (1.f + expf(-a.x));
      a.y = a.y / (1.f + expf(-a.y));
      a.z = a.z / (1.f + expf(-a.z));
      a.w = a.w / (1.f + expf(-a.w));
      *reinterpret_cast<float4*>(out + (size_t)grow * C + c0) = a;
    }
  }
}

extern "C" void kernel_launch(void* const* d_in, const int* in_sizes, int n_in,
                              void* d_out, int out_size, void* d_ws, size_t ws_size,
                              hipStream_t stream) {
  const float* feat   = (const float*)d_in[0];
  const float* coords = (const float*)d_in[1];
  const int*   knn    = (const int*)d_in[2];
  const float* W      = (const float*)d_in[3];
  const float* bias   = (const float*)d_in[4];
  float* out = (float*)d_out;

  const int n = in_sizes[0] / C;                 // 50000
  const int grid = (n + BM - 1) / BM;            // 1563

  hipLaunchKernelGGL(gcl_fused, dim3(grid), dim3(NTHREADS), 0, stream,
                     feat, coords, knn, W, bias, out, n);
}

// Round 2
// 162.745 us; speedup vs baseline: 2.6641x; 2.6641x over previous
//
#include <hip/hip_runtime.h>
#include <math.h>

// GraphConvLayer, round 2: bf16 gather table + MFMA GEMM.
//  prep_feat: feat f32 -> bf16 table in ws (halves gather bytes)
//  prep_w:    W (518,256) -> Wt (256,544) bf16, zero-padded, n-major
//  gcl_main:  per block 32 rows: bf16 gather-mean -> LDS mix[32][544(+pad)],
//             coord stats, then 16x16x32 bf16 MFMA GEMM (k-permutation-invariant
//             operand loads), SiLU epilogue.
// Fallback to the round-1 all-f32 kernel if ws too small.

typedef __attribute__((ext_vector_type(8))) short short8;
typedef __attribute__((ext_vector_type(4))) float f32x4;

constexpr int K = 32;
constexpr int C = 256;
constexpr int IN_DIM = 2 * C + 6;    // 518
constexpr int KP = 544;              // padded K (17 * 32)
constexpr int BM = 32;               // rows per block
constexpr int MIXS = 552;            // LDS row stride (bf16): 1104 B, 276 words == 20 mod 32
constexpr int NT = 256;

__device__ __forceinline__ float bf_lo(unsigned u) {
  union { unsigned x; float f; } c; c.x = u << 16; return c.f;
}
__device__ __forceinline__ float bf_hi(unsigned u) {
  union { unsigned x; float f; } c; c.x = u & 0xffff0000u; return c.f;
}
__device__ __forceinline__ unsigned short f2bf(float f) {
  union { float f; unsigned u; } c; c.f = f;
  return (unsigned short)((c.u + 0x7fffu + ((c.u >> 16) & 1u)) >> 16);
}
__device__ __forceinline__ unsigned pack2(float lo, float hi) {
  return (unsigned)f2bf(lo) | ((unsigned)f2bf(hi) << 16);
}

// ---------------- prep kernels ----------------
__global__ __launch_bounds__(256) void prep_feat(const float* __restrict__ feat,
                                                 unsigned* __restrict__ featb,
                                                 long total4) {
  long i = (long)blockIdx.x * 256 + threadIdx.x;   // 4 floats -> 2 packed uints
  if (i < total4) {
    float4 v = reinterpret_cast<const float4*>(feat)[i];
    uint2 o; o.x = pack2(v.x, v.y); o.y = pack2(v.z, v.w);
    reinterpret_cast<uint2*>(featb)[i] = o;
  }
}

__global__ __launch_bounds__(256) void prep_w(const float* __restrict__ W,
                                              unsigned short* __restrict__ Wt) {
  int i = blockIdx.x * 256 + threadIdx.x;          // over 256*544
  if (i < C * KP) {
    int nn = i / KP, k = i - nn * KP;
    float v = (k < IN_DIM) ? W[(size_t)k * C + nn] : 0.f;
    Wt[i] = f2bf(v);
  }
}

// ---------------- main fused kernel ----------------
__global__ __launch_bounds__(NT, 4)
void gcl_main(const unsigned short* __restrict__ featb,
              const float* __restrict__ coords,
              const int*   __restrict__ knn,
              const unsigned short* __restrict__ Wt,
              const float* __restrict__ bias,
              float* __restrict__ out, int n)
{
  __shared__ unsigned short mix[BM][MIXS];
  __shared__ int knnLds[BM * K];

  const int t = threadIdx.x;
  const int row0 = blockIdx.x * BM;

  // knn indices -> LDS (coalesced)
  #pragma unroll
  for (int i = 0; i < (BM * K) / NT; ++i) {
    int e = t + i * NT;
    int r = e >> 5, k = e & 31;
    int g = row0 + r; if (g >= n) g = n - 1;
    knnLds[e] = knn[(size_t)g * K + k];
  }
  // zero-pad mix cols 518..543
  for (int e = t; e < BM * (KP - IN_DIM); e += NT) {
    int r = e / (KP - IN_DIM), c = e - r * (KP - IN_DIM);
    mix[r][IN_DIM + c] = 0;
  }
  __syncthreads();

  const int w    = t >> 6;       // wave 0..3
  const int lane = t & 63;
  const int half = lane >> 5;    // row within pair
  const int cl   = lane & 31;    // channel octet: channels cl*8..cl*8+7

  // gather-mean + self copy: wave handles rows 8w..8w+7 as 4 row-pairs
  for (int p = 0; p < 4; ++p) {
    const int r = (w << 3) + (p << 1) + half;
    int g = row0 + r; if (g >= n) g = n - 1;
    uint4 self = *reinterpret_cast<const uint4*>(featb + (size_t)g * C + cl * 8);
    *reinterpret_cast<uint4*>(&mix[r][cl * 8]) = self;
    const int* ids = &knnLds[r * K];
    float a0 = 0, a1 = 0, a2 = 0, a3 = 0, a4 = 0, a5 = 0, a6 = 0, a7 = 0;
    #pragma unroll 8
    for (int k = 0; k < K; ++k) {
      uint4 v = *reinterpret_cast<const uint4*>(featb + (size_t)ids[k] * C + cl * 8);
      a0 += bf_lo(v.x); a1 += bf_hi(v.x);
      a2 += bf_lo(v.y); a3 += bf_hi(v.y);
      a4 += bf_lo(v.z); a5 += bf_hi(v.z);
      a6 += bf_lo(v.w); a7 += bf_hi(v.w);
    }
    const float s = 1.0f / 32.0f;
    uint4 o;
    o.x = pack2(a0 * s, a1 * s); o.y = pack2(a2 * s, a3 * s);
    o.z = pack2(a4 * s, a5 * s); o.w = pack2(a6 * s, a7 * s);
    *reinterpret_cast<uint4*>(&mix[r][C + cl * 8]) = o;
  }

  // relative coordinate statistics (96 threads: one per (row,dim))
  if (t < BM * 3) {
    const int r = t / 3, d = t - r * 3;
    int g = row0 + r; if (g >= n) g = n - 1;
    const int* ids = &knnLds[r * K];
    float s = 0.f, ss = 0.f;
    #pragma unroll 8
    for (int k = 0; k < K; ++k) {
      float v = coords[(size_t)ids[k] * 3 + d];
      s += v; ss += v * v;
    }
    const float m = s * (1.0f / 32.0f);
    const float var = ss * (1.0f / 32.0f) - m * m;   // var(rel)==var(nbr)
    mix[r][2 * C + d]     = f2bf(m - coords[(size_t)g * 3 + d]);
    mix[r][2 * C + 3 + d] = f2bf(sqrtf(fmaxf(var, 0.f)));
  }
  __syncthreads();

  // ---- MFMA GEMM: wave w -> output cols n0..n0+63, all 32 rows ----
  const int n0  = w * 64;
  const int l15 = lane & 15;
  const int h   = lane >> 4;

  f32x4 acc[2][4];
  #pragma unroll
  for (int mt = 0; mt < 2; ++mt)
    #pragma unroll
    for (int nt = 0; nt < 4; ++nt)
      acc[mt][nt] = (f32x4){0.f, 0.f, 0.f, 0.f};

  const unsigned short* wbase = Wt + (size_t)(n0 + l15) * KP + 8 * h;

  #pragma unroll 1
  for (int s8 = 0; s8 < KP / 32; ++s8) {
    const int kb = s8 * 32;
    // A-slot i <- mix[m][kb + 8h + i]; B-slot i <- Wt[nn][kb + 8h + i]:
    // identical k-mapping on both operands -> result invariant to the
    // hardware's internal k layout (only C/D layout, measured, matters).
    short8 A0 = *reinterpret_cast<const short8*>(&mix[l15][kb + 8 * h]);
    short8 A1 = *reinterpret_cast<const short8*>(&mix[16 + l15][kb + 8 * h]);
    short8 B0 = *reinterpret_cast<const short8*>(wbase + 0 * 16 * KP + kb);
    short8 B1 = *reinterpret_cast<const short8*>(wbase + 1 * 16 * KP + kb);
    short8 B2 = *reinterpret_cast<const short8*>(wbase + 2 * 16 * KP + kb);
    short8 B3 = *reinterpret_cast<const short8*>(wbase + 3 * 16 * KP + kb);
    acc[0][0] = __builtin_amdgcn_mfma_f32_16x16x32_bf16(A0, B0, acc[0][0], 0, 0, 0);
    acc[1][0] = __builtin_amdgcn_mfma_f32_16x16x32_bf16(A1, B0, acc[1][0], 0, 0, 0);
    acc[0][1] = __builtin_amdgcn_mfma_f32_16x16x32_bf16(A0, B1, acc[0][1], 0, 0, 0);
    acc[1][1] = __builtin_amdgcn_mfma_f32_16x16x32_bf16(A1, B1, acc[1][1], 0, 0, 0);
    acc[0][2] = __builtin_amdgcn_mfma_f32_16x16x32_bf16(A0, B2, acc[0][2], 0, 0, 0);
    acc[1][2] = __builtin_amdgcn_mfma_f32_16x16x32_bf16(A1, B2, acc[1][2], 0, 0, 0);
    acc[0][3] = __builtin_amdgcn_mfma_f32_16x16x32_bf16(A0, B3, acc[0][3], 0, 0, 0);
    acc[1][3] = __builtin_amdgcn_mfma_f32_16x16x32_bf16(A1, B3, acc[1][3], 0, 0, 0);
  }

  // epilogue: bias + SiLU + store (C/D layout: col=lane&15, row=(lane>>4)*4+q)
  #pragma unroll
  for (int mt = 0; mt < 2; ++mt) {
    #pragma unroll
    for (int nt = 0; nt < 4; ++nt) {
      const int col = n0 + nt * 16 + l15;
      const float bv = bias[col];
      f32x4 a = acc[mt][nt];
      #pragma unroll
      for (int q = 0; q < 4; ++q) {
        const int grow = row0 + mt * 16 + 4 * h + q;
        if (grow < n) {
          const float x = a[q] + bv;
          out[(size_t)grow * C + col] = x / (1.f + expf(-x));
        }
      }
    }
  }
}

// ---------------- round-1 f32 fallback (ws too small) ----------------
constexpr int MIX_STRIDE = 520;

#define FMA4(mcomp, wv)                                                        \
  a.x = fmaf((mcomp), (wv).x, a.x);                                            \
  a.y = fmaf((mcomp), (wv).y, a.y);                                            \
  a.z = fmaf((mcomp), (wv).z, a.z);                                            \
  a.w = fmaf((mcomp), (wv).w, a.w);

__global__ __launch_bounds__(256, 2)
void gcl_fused(const float* __restrict__ feat,
               const float* __restrict__ coords,
               const int*   __restrict__ knn,
               const float* __restrict__ W,
               const float* __restrict__ bias,
               float* __restrict__ out,
               int n)
{
  __shared__ float mix[BM][MIX_STRIDE];
  __shared__ int   knnLds[BM * K];

  const int t = threadIdx.x;
  const int row0 = blockIdx.x * BM;

  #pragma unroll
  for (int i = 0; i < (BM * K) / 256; ++i) {
    const int e = t + i * 256;
    const int r = e >> 5;
    const int k = e & (K - 1);
    int grow = row0 + r; if (grow >= n) grow = n - 1;
    knnLds[e] = knn[(size_t)grow * K + k];
  }
  __syncthreads();

  const int c4 = t & 63;
  const int rg = t >> 6;

  for (int ri = 0; ri < BM / 4; ++ri) {
    const int r = rg * (BM / 4) + ri;
    int grow = row0 + r; if (grow >= n) grow = n - 1;
    const int* ids = &knnLds[r * K];
    float sx = 0.f, sy = 0.f, sz = 0.f, sw = 0.f;
    #pragma unroll 8
    for (int k = 0; k < K; ++k) {
      const float4 f = *reinterpret_cast<const float4*>(feat + (size_t)ids[k] * C + c4 * 4);
      sx += f.x; sy += f.y; sz += f.z; sw += f.w;
    }
    const float4 self = *reinterpret_cast<const float4*>(feat + (size_t)grow * C + c4 * 4);
    float* mr = mix[r];
    *reinterpret_cast<float4*>(mr + c4 * 4) = self;
    const float inv = 1.0f / (float)K;
    float4 a; a.x = sx * inv; a.y = sy * inv; a.z = sz * inv; a.w = sw * inv;
    *reinterpret_cast<float4*>(mr + C + c4 * 4) = a;
  }

  if (t < BM * 3) {
    const int r = t / 3;
    const int d = t - r * 3;
    int grow = row0 + r; if (grow >= n) grow = n - 1;
    const int* ids = &knnLds[r * K];
    float s = 0.f, ss = 0.f;
    #pragma unroll 8
    for (int k = 0; k < K; ++k) {
      const float v = coords[(size_t)ids[k] * 3 + d];
      s += v; ss += v * v;
    }
    const float inv = 1.0f / (float)K;
    const float m = s * inv;
    const float var = ss * inv - m * m;
    mix[r][2 * C + d]     = m - coords[(size_t)grow * 3 + d];
    mix[r][2 * C + 3 + d] = sqrtf(fmaxf(var, 0.f));
  }
  __syncthreads();

  const int c0 = (t & 63) * 4;
  const int rbase = rg * (BM / 4);

  float4 acc[BM / 4];
  {
    const float4 bv = *reinterpret_cast<const float4*>(bias + c0);
    #pragma unroll
    for (int ri = 0; ri < BM / 4; ++ri) acc[ri] = bv;
  }

  for (int jb = 0; jb < 129; ++jb) {
    const int j = jb * 4;
    const float4 w0 = *reinterpret_cast<const float4*>(W + (size_t)(j + 0) * C + c0);
    const float4 w1 = *reinterpret_cast<const float4*>(W + (size_t)(j + 1) * C + c0);
    const float4 w2 = *reinterpret_cast<const float4*>(W + (size_t)(j + 2) * C + c0);
    const float4 w3 = *reinterpret_cast<const float4*>(W + (size_t)(j + 3) * C + c0);
    #pragma unroll
    for (int ri = 0; ri < BM / 4; ++ri) {
      const float4 m4 = *reinterpret_cast<const float4*>(&mix[rbase + ri][j]);
      float4 a = acc[ri];
      FMA4(m4.x, w0)
      FMA4(m4.y, w1)
      FMA4(m4.z, w2)
      FMA4(m4.w, w3)
      acc[ri] = a;
    }
  }
  #pragma unroll
  for (int jt = IN_DIM - 2; jt < IN_DIM; ++jt) {
    const float4 wv = *reinterpret_cast<const float4*>(W + (size_t)jt * C + c0);
    #pragma unroll
    for (int ri = 0; ri < BM / 4; ++ri) {
      const float m = mix[rbase + ri][jt];
      float4 a = acc[ri];
      FMA4(m, wv)
      acc[ri] = a;
    }
  }

  #pragma unroll
  for (int ri = 0; ri < BM / 4; ++ri) {
    const int grow = row0 + rbase + ri;
    if (grow < n) {
      float4 a = acc[ri];
      a.x = a.x / (1.f + expf(-a.x));
      a.y = a.y / (1.f + expf(-a.y));
      a.z = a.z / (1.f + expf(-a.z));
      a.w = a.w / (1.f + expf(-a.w));
      *reinterpret_cast<float4*>(out + (size_t)grow * C + c0) = a;
    }
  }
}

extern "C" void kernel_launch(void* const* d_in, const int* in_sizes, int n_in,
                              void* d_out, int out_size, void* d_ws, size_t ws_size,
                              hipStream_t stream) {
  const float* feat   = (const float*)d_in[0];
  const float* coords = (const float*)d_in[1];
  const int*   knn    = (const int*)d_in[2];
  const float* W      = (const float*)d_in[3];
  const float* bias   = (const float*)d_in[4];
  float* out = (float*)d_out;

  const int n = in_sizes[0] / C;                 // 50000
  const int grid = (n + BM - 1) / BM;            // 1563

  const size_t featb_bytes = (size_t)n * C * 2;  // 25.6 MB
  const size_t wt_bytes    = (size_t)C * KP * 2; // 278 KB

  if (ws_size >= featb_bytes + wt_bytes) {
    unsigned short* featb = (unsigned short*)d_ws;
    unsigned short* Wt    = (unsigned short*)((char*)d_ws + featb_bytes);
    const long total4 = (long)n * C / 4;
    hipLaunchKernelGGL(prep_feat, dim3((unsigned)((total4 + 255) / 256)), dim3(256), 0, stream,
                       feat, (unsigned*)featb, total4);
    hipLaunchKernelGGL(prep_w, dim3((C * KP + 255) / 256), dim3(256), 0, stream, W, Wt);
    hipLaunchKernelGGL(gcl_main, dim3(grid), dim3(NT), 0, stream,
                       featb, coords, knn, Wt, bias, out, n);
  } else {
    hipLaunchKernelGGL(gcl_fused, dim3(grid), dim3(256), 0, stream,
                       feat, coords, knn, W, bias, out, n);
  }
}

// Round 3
// 126.564 us; speedup vs baseline: 3.4257x; 1.2859x over previous
//
#include <hip/hip_runtime.h>
#include <math.h>

// GraphConvLayer, round 3: fp8 gather table.
//  prep_feat_q: feat f32 -> fp8 e4m3 table in ws (quarters gather bytes vs f32)
//  prep_w:      W (518,256) -> Wt (256,544) bf16, n-major
//  gcl_main:    per block 32 rows: fp8 gather-mean (hw cvt_pk_f32_fp8 decode),
//               self-feat from f32 feat (keeps precision), coord stats ->
//               LDS mix[32][552] bf16, then 16x16x32 bf16 MFMA GEMM, SiLU.
// Fallback to round-1 f32 kernel if ws too small.

typedef __attribute__((ext_vector_type(8))) short short8;
typedef __attribute__((ext_vector_type(4))) float f32x4;
typedef __attribute__((ext_vector_type(2))) float f32x2;

constexpr int K = 32;
constexpr int C = 256;
constexpr int IN_DIM = 2 * C + 6;    // 518
constexpr int KP = 544;              // padded GEMM-K (17 * 32)
constexpr int BM = 32;               // rows per block
constexpr int MIXS = 552;            // LDS row stride (bf16): 1104 B, 16B-aligned
constexpr int NT = 256;

__device__ __forceinline__ unsigned short f2bf(float f) {
  union { float f; unsigned u; } c; c.f = f;
  return (unsigned short)((c.u + 0x7fffu + ((c.u >> 16) & 1u)) >> 16);
}
__device__ __forceinline__ unsigned pack2(float lo, float hi) {
  return (unsigned)f2bf(lo) | ((unsigned)f2bf(hi) << 16);
}

// ---------------- prep kernels ----------------
__global__ __launch_bounds__(256) void prep_feat_q(const float* __restrict__ feat,
                                                   uint2* __restrict__ featq,
                                                   long total8) {
  long i = (long)blockIdx.x * 256 + threadIdx.x;   // 8 floats -> uint2 of fp8
  if (i < total8) {
    const float4 v0 = reinterpret_cast<const float4*>(feat)[2 * i];
    const float4 v1 = reinterpret_cast<const float4*>(feat)[2 * i + 1];
    unsigned a = 0, b = 0;
    a = __builtin_amdgcn_cvt_pk_fp8_f32(v0.x, v0.y, a, false);
    a = __builtin_amdgcn_cvt_pk_fp8_f32(v0.z, v0.w, a, true);
    b = __builtin_amdgcn_cvt_pk_fp8_f32(v1.x, v1.y, b, false);
    b = __builtin_amdgcn_cvt_pk_fp8_f32(v1.z, v1.w, b, true);
    uint2 o; o.x = a; o.y = b;
    featq[i] = o;
  }
}

__global__ __launch_bounds__(256) void prep_w(const float* __restrict__ W,
                                              unsigned short* __restrict__ Wt) {
  int i = blockIdx.x * 256 + threadIdx.x;          // over 256*544
  if (i < C * KP) {
    int nn = i / KP, k = i - nn * KP;
    float v = (k < IN_DIM) ? W[(size_t)k * C + nn] : 0.f;
    Wt[i] = f2bf(v);
  }
}

// ---------------- main fused kernel ----------------
__global__ __launch_bounds__(NT, 4)
void gcl_main(const unsigned char* __restrict__ featq,   // fp8 table (N x C)
              const float* __restrict__ feat,            // original f32 (self rows)
              const float* __restrict__ coords,
              const int*   __restrict__ knn,
              const unsigned short* __restrict__ Wt,
              const float* __restrict__ bias,
              float* __restrict__ out, int n)
{
  __shared__ unsigned short mix[BM][MIXS];
  __shared__ int knnLds[BM * K];

  const int t = threadIdx.x;
  const int row0 = blockIdx.x * BM;

  // knn indices -> LDS (coalesced)
  #pragma unroll
  for (int i = 0; i < (BM * K) / NT; ++i) {
    int e = t + i * NT;
    int r = e >> 5, k = e & 31;
    int g = row0 + r; if (g >= n) g = n - 1;
    knnLds[e] = knn[(size_t)g * K + k];
  }
  // zero-pad mix cols 518..543
  for (int e = t; e < BM * (KP - IN_DIM); e += NT) {
    int r = e / (KP - IN_DIM), c = e - r * (KP - IN_DIM);
    mix[r][IN_DIM + c] = 0;
  }
  __syncthreads();

  const int w    = t >> 6;       // wave 0..3
  const int lane = t & 63;
  const int cl   = lane & 15;    // channel group: channels cl*16 .. cl*16+15
  const int rq   = lane >> 4;    // row-in-quad 0..3

  // gather-mean (fp8) + self copy (f32): wave handles rows 8w..8w+7 in 2 quads
  #pragma unroll
  for (int p = 0; p < 2; ++p) {
    const int r = (w << 3) + (p << 2) + rq;
    int g = row0 + r; if (g >= n) g = n - 1;

    // self feature row, f32 -> bf16
    {
      const float4 s0 = *reinterpret_cast<const float4*>(feat + (size_t)g * C + cl * 16 + 0);
      const float4 s1 = *reinterpret_cast<const float4*>(feat + (size_t)g * C + cl * 16 + 4);
      const float4 s2 = *reinterpret_cast<const float4*>(feat + (size_t)g * C + cl * 16 + 8);
      const float4 s3 = *reinterpret_cast<const float4*>(feat + (size_t)g * C + cl * 16 + 12);
      uint4 o0, o1;
      o0.x = pack2(s0.x, s0.y); o0.y = pack2(s0.z, s0.w);
      o0.z = pack2(s1.x, s1.y); o0.w = pack2(s1.z, s1.w);
      o1.x = pack2(s2.x, s2.y); o1.y = pack2(s2.z, s2.w);
      o1.z = pack2(s3.x, s3.y); o1.w = pack2(s3.z, s3.w);
      *reinterpret_cast<uint4*>(&mix[r][cl * 16 + 0]) = o0;
      *reinterpret_cast<uint4*>(&mix[r][cl * 16 + 8]) = o1;
    }

    const int* ids = &knnLds[r * K];
    float a0=0,a1=0,a2=0,a3=0,a4=0,a5=0,a6=0,a7=0;
    float a8=0,a9=0,aA=0,aB=0,aC=0,aD=0,aE=0,aF=0;
    #pragma unroll 8
    for (int k = 0; k < K; ++k) {
      const uint4 v = *reinterpret_cast<const uint4*>(featq + (size_t)ids[k] * C + cl * 16);
      f32x2 d0 = __builtin_amdgcn_cvt_pk_f32_fp8(v.x, false);
      f32x2 d1 = __builtin_amdgcn_cvt_pk_f32_fp8(v.x, true);
      f32x2 d2 = __builtin_amdgcn_cvt_pk_f32_fp8(v.y, false);
      f32x2 d3 = __builtin_amdgcn_cvt_pk_f32_fp8(v.y, true);
      f32x2 d4 = __builtin_amdgcn_cvt_pk_f32_fp8(v.z, false);
      f32x2 d5 = __builtin_amdgcn_cvt_pk_f32_fp8(v.z, true);
      f32x2 d6 = __builtin_amdgcn_cvt_pk_f32_fp8(v.w, false);
      f32x2 d7 = __builtin_amdgcn_cvt_pk_f32_fp8(v.w, true);
      a0 += d0.x; a1 += d0.y; a2 += d1.x; a3 += d1.y;
      a4 += d2.x; a5 += d2.y; a6 += d3.x; a7 += d3.y;
      a8 += d4.x; a9 += d4.y; aA += d5.x; aB += d5.y;
      aC += d6.x; aD += d6.y; aE += d7.x; aF += d7.y;
    }
    const float s = 1.0f / 32.0f;
    uint4 o0, o1;
    o0.x = pack2(a0 * s, a1 * s); o0.y = pack2(a2 * s, a3 * s);
    o0.z = pack2(a4 * s, a5 * s); o0.w = pack2(a6 * s, a7 * s);
    o1.x = pack2(a8 * s, a9 * s); o1.y = pack2(aA * s, aB * s);
    o1.z = pack2(aC * s, aD * s); o1.w = pack2(aE * s, aF * s);
    *reinterpret_cast<uint4*>(&mix[r][C + cl * 16 + 0]) = o0;
    *reinterpret_cast<uint4*>(&mix[r][C + cl * 16 + 8]) = o1;
  }

  // relative coordinate statistics (96 threads: one per (row,dim))
  if (t < BM * 3) {
    const int r = t / 3, d = t - r * 3;
    int g = row0 + r; if (g >= n) g = n - 1;
    const int* ids = &knnLds[r * K];
    float s = 0.f, ss = 0.f;
    #pragma unroll 8
    for (int k = 0; k < K; ++k) {
      float v = coords[(size_t)ids[k] * 3 + d];
      s += v; ss += v * v;
    }
    const float m = s * (1.0f / 32.0f);
    const float var = ss * (1.0f / 32.0f) - m * m;   // var(rel)==var(nbr)
    mix[r][2 * C + d]     = f2bf(m - coords[(size_t)g * 3 + d]);
    mix[r][2 * C + 3 + d] = f2bf(sqrtf(fmaxf(var, 0.f)));
  }
  __syncthreads();

  // ---- MFMA GEMM: wave w -> output cols n0..n0+63, all 32 rows ----
  const int n0  = w * 64;
  const int l15 = lane & 15;
  const int h   = lane >> 4;

  f32x4 acc[2][4];
  #pragma unroll
  for (int mt = 0; mt < 2; ++mt)
    #pragma unroll
    for (int nt = 0; nt < 4; ++nt)
      acc[mt][nt] = (f32x4){0.f, 0.f, 0.f, 0.f};

  const unsigned short* wbase = Wt + (size_t)(n0 + l15) * KP + 8 * h;

  #pragma unroll 1
  for (int s8 = 0; s8 < KP / 32; ++s8) {
    const int kb = s8 * 32;
    // A-slot i <- mix[m][kb + 8h + i]; B-slot i <- Wt[nn][kb + 8h + i]:
    // identical k-mapping on both operands -> k-layout-permutation invariant.
    short8 A0 = *reinterpret_cast<const short8*>(&mix[l15][kb + 8 * h]);
    short8 A1 = *reinterpret_cast<const short8*>(&mix[16 + l15][kb + 8 * h]);
    short8 B0 = *reinterpret_cast<const short8*>(wbase + 0 * 16 * KP + kb);
    short8 B1 = *reinterpret_cast<const short8*>(wbase + 1 * 16 * KP + kb);
    short8 B2 = *reinterpret_cast<const short8*>(wbase + 2 * 16 * KP + kb);
    short8 B3 = *reinterpret_cast<const short8*>(wbase + 3 * 16 * KP + kb);
    acc[0][0] = __builtin_amdgcn_mfma_f32_16x16x32_bf16(A0, B0, acc[0][0], 0, 0, 0);
    acc[1][0] = __builtin_amdgcn_mfma_f32_16x16x32_bf16(A1, B0, acc[1][0], 0, 0, 0);
    acc[0][1] = __builtin_amdgcn_mfma_f32_16x16x32_bf16(A0, B1, acc[0][1], 0, 0, 0);
    acc[1][1] = __builtin_amdgcn_mfma_f32_16x16x32_bf16(A1, B1, acc[1][1], 0, 0, 0);
    acc[0][2] = __builtin_amdgcn_mfma_f32_16x16x32_bf16(A0, B2, acc[0][2], 0, 0, 0);
    acc[1][2] = __builtin_amdgcn_mfma_f32_16x16x32_bf16(A1, B2, acc[1][2], 0, 0, 0);
    acc[0][3] = __builtin_amdgcn_mfma_f32_16x16x32_bf16(A0, B3, acc[0][3], 0, 0, 0);
    acc[1][3] = __builtin_amdgcn_mfma_f32_16x16x32_bf16(A1, B3, acc[1][3], 0, 0, 0);
  }

  // epilogue: bias + SiLU + store (C/D layout: col=lane&15, row=(lane>>4)*4+q)
  #pragma unroll
  for (int mt = 0; mt < 2; ++mt) {
    #pragma unroll
    for (int nt = 0; nt < 4; ++nt) {
      const int col = n0 + nt * 16 + l15;
      const float bv = bias[col];
      f32x4 a = acc[mt][nt];
      #pragma unroll
      for (int q = 0; q < 4; ++q) {
        const int grow = row0 + mt * 16 + 4 * h + q;
        if (grow < n) {
          const float x = a[q] + bv;
          out[(size_t)grow * C + col] = x / (1.f + __expf(-x));
        }
      }
    }
  }
}

// ---------------- round-1 f32 fallback (ws too small) ----------------
constexpr int MIX_STRIDE = 520;

#define FMA4(mcomp, wv)                                                        \
  a.x = fmaf((mcomp), (wv).x, a.x);                                            \
  a.y = fmaf((mcomp), (wv).y, a.y);                                            \
  a.z = fmaf((mcomp), (wv).z, a.z);                                            \
  a.w = fmaf((mcomp), (wv).w, a.w);

__global__ __launch_bounds__(256, 2)
void gcl_fused(const float* __restrict__ feat,
               const float* __restrict__ coords,
               const int*   __restrict__ knn,
               const float* __restrict__ W,
               const float* __restrict__ bias,
               float* __restrict__ out,
               int n)
{
  __shared__ float mix[BM][MIX_STRIDE];
  __shared__ int   knnLds[BM * K];

  const int t = threadIdx.x;
  const int row0 = blockIdx.x * BM;

  #pragma unroll
  for (int i = 0; i < (BM * K) / 256; ++i) {
    const int e = t + i * 256;
    const int r = e >> 5;
    const int k = e & (K - 1);
    int grow = row0 + r; if (grow >= n) grow = n - 1;
    knnLds[e] = knn[(size_t)grow * K + k];
  }
  __syncthreads();

  const int c4 = t & 63;
  const int rg = t >> 6;

  for (int ri = 0; ri < BM / 4; ++ri) {
    const int r = rg * (BM / 4) + ri;
    int grow = row0 + r; if (grow >= n) grow = n - 1;
    const int* ids = &knnLds[r * K];
    float sx = 0.f, sy = 0.f, sz = 0.f, sw = 0.f;
    #pragma unroll 8
    for (int k = 0; k < K; ++k) {
      const float4 f = *reinterpret_cast<const float4*>(feat + (size_t)ids[k] * C + c4 * 4);
      sx += f.x; sy += f.y; sz += f.z; sw += f.w;
    }
    const float4 self = *reinterpret_cast<const float4*>(feat + (size_t)grow * C + c4 * 4);
    float* mr = mix[r];
    *reinterpret_cast<float4*>(mr + c4 * 4) = self;
    const float inv = 1.0f / (float)K;
    float4 a; a.x = sx * inv; a.y = sy * inv; a.z = sz * inv; a.w = sw * inv;
    *reinterpret_cast<float4*>(mr + C + c4 * 4) = a;
  }

  if (t < BM * 3) {
    const int r = t / 3;
    const int d = t - r * 3;
    int grow = row0 + r; if (grow >= n) grow = n - 1;
    const int* ids = &knnLds[r * K];
    float s = 0.f, ss = 0.f;
    #pragma unroll 8
    for (int k = 0; k < K; ++k) {
      const float v = coords[(size_t)ids[k] * 3 + d];
      s += v; ss += v * v;
    }
    const float inv = 1.0f / (float)K;
    const float m = s * inv;
    const float var = ss * inv - m * m;
    mix[r][2 * C + d]     = m - coords[(size_t)grow * 3 + d];
    mix[r][2 * C + 3 + d] = sqrtf(fmaxf(var, 0.f));
  }
  __syncthreads();

  const int c0 = (t & 63) * 4;
  const int rbase = rg * (BM / 4);

  float4 acc[BM / 4];
  {
    const float4 bv = *reinterpret_cast<const float4*>(bias + c0);
    #pragma unroll
    for (int ri = 0; ri < BM / 4; ++ri) acc[ri] = bv;
  }

  for (int jb = 0; jb < 129; ++jb) {
    const int j = jb * 4;
    const float4 w0 = *reinterpret_cast<const float4*>(W + (size_t)(j + 0) * C + c0);
    const float4 w1 = *reinterpret_cast<const float4*>(W + (size_t)(j + 1) * C + c0);
    const float4 w2 = *reinterpret_cast<const float4*>(W + (size_t)(j + 2) * C + c0);
    const float4 w3 = *reinterpret_cast<const float4*>(W + (size_t)(j + 3) * C + c0);
    #pragma unroll
    for (int ri = 0; ri < BM / 4; ++ri) {
      const float4 m4 = *reinterpret_cast<const float4*>(&mix[rbase + ri][j]);
      float4 a = acc[ri];
      FMA4(m4.x, w0)
      FMA4(m4.y, w1)
      FMA4(m4.z, w2)
      FMA4(m4.w, w3)
      acc[ri] = a;
    }
  }
  #pragma unroll
  for (int jt = IN_DIM - 2; jt < IN_DIM; ++jt) {
    const float4 wv = *reinterpret_cast<const float4*>(W + (size_t)jt * C + c0);
    #pragma unroll
    for (int ri = 0; ri < BM / 4; ++ri) {
      const float m = mix[rbase + ri][jt];
      float4 a = acc[ri];
      FMA4(m, wv)
      acc[ri] = a;
    }
  }

  #pragma unroll
  for (int ri = 0; ri < BM / 4; ++ri) {
    const int grow = row0 + rbase + ri;
    if (grow < n) {
      float4 a = acc[ri];
      a.x = a.x / (1.f + expf(-a.x));
      a.y = a.y / (1.f + expf(-a.y));
      a.z = a.z / (1.f + expf(-a.z));
      a.w = a.w / (1.f + expf(-a.w));
      *reinterpret_cast<float4*>(out + (size_t)grow * C + c0) = a;
    }
  }
}

extern "C" void kernel_launch(void* const* d_in, const int* in_sizes, int n_in,
                              void* d_out, int out_size, void* d_ws, size_t ws_size,
                              hipStream_t stream) {
  const float* feat   = (const float*)d_in[0];
  const float* coords = (const float*)d_in[1];
  const int*   knn    = (const int*)d_in[2];
  const float* W      = (const float*)d_in[3];
  const float* bias   = (const float*)d_in[4];
  float* out = (float*)d_out;

  const int n = in_sizes[0] / C;                 // 50000
  const int grid = (n + BM - 1) / BM;            // 1563

  const size_t featq_bytes = (size_t)n * C;      // 12.8 MB fp8
  const size_t wt_bytes    = (size_t)C * KP * 2; // 278 KB

  if (ws_size >= featq_bytes + wt_bytes) {
    unsigned char* featq  = (unsigned char*)d_ws;
    unsigned short* Wt    = (unsigned short*)((char*)d_ws + featq_bytes);
    const long total8 = (long)n * C / 8;
    hipLaunchKernelGGL(prep_feat_q, dim3((unsigned)((total8 + 255) / 256)), dim3(256), 0, stream,
                       feat, (uint2*)featq, total8);
    hipLaunchKernelGGL(prep_w, dim3((C * KP + 255) / 256), dim3(256), 0, stream, W, Wt);
    hipLaunchKernelGGL(gcl_main, dim3(grid), dim3(NT), 0, stream,
                       featq, feat, coords, knn, Wt, bias, out, n);
  } else {
    hipLaunchKernelGGL(gcl_fused, dim3(grid), dim3(256), 0, stream,
                       feat, coords, knn, W, bias, out, n);
  }
}